// Round 6
// baseline (423.976 us; speedup 1.0000x reference)
//
#include <hip/hip_runtime.h>
#include <cstddef>
#include <cstdint>

#define DIM   7168
#define NEXP  256
#define NTOK  8192
#define BM    64
#define BK    32

typedef _Float16 f16;
typedef __attribute__((ext_vector_type(8))) _Float16 f16x8;
typedef __attribute__((ext_vector_type(4))) float    f32x4;

// ---------------- W pre-convert: f32 -> f16 hi + f16 lo ---------------------
__global__ __launch_bounds__(256) void wconv(const float* __restrict__ W,
                                             f16* __restrict__ Whi,
                                             f16* __restrict__ Wlo) {
  const int i = (blockIdx.x * 256 + threadIdx.x) * 4;
  const float4 v = *reinterpret_cast<const float4*>(W + i);
  f16 h0 = (f16)v.x, h1 = (f16)v.y, h2 = (f16)v.z, h3 = (f16)v.w;
  f16 l0 = (f16)(v.x - (float)h0), l1 = (f16)(v.y - (float)h1);
  f16 l2 = (f16)(v.z - (float)h2), l3 = (f16)(v.w - (float)h3);
  __attribute__((ext_vector_type(4))) _Float16 hv = {h0, h1, h2, h3};
  __attribute__((ext_vector_type(4))) _Float16 lv = {l0, l1, l2, l3};
  *reinterpret_cast<decltype(hv)*>(Whi + i) = hv;
  *reinterpret_cast<decltype(lv)*>(Wlo + i) = lv;
}

// ---------------- MFMA GEMM: Lp[m][n] = sum_k X[m][k] * W[n][k] -------------
// fp16 3-term split, double-buffered LDS + COUNTED vmcnt pipeline (T3+T4):
// per iter: aload(t+1); stageB(nxt,t+1) [8 gload_lds stay in flight];
//           awrite(nxt) [compiler waits vmcnt(8) = A only];
//           compute(cur); lgkmcnt(0); raw s_barrier.  NO vmcnt(0) in loop.
__global__ __launch_bounds__(256, 2) void gemm_mfma(const float* __restrict__ X,
                                                    const f16* __restrict__ Whi,
                                                    const f16* __restrict__ Wlo,
                                                    float* __restrict__ L,
                                                    int ktiles) {
  __shared__ __align__(16) f16 Ah[2][BM * BK];     // 2 x 4 KB
  __shared__ __align__(16) f16 Al[2][BM * BK];     // 2 x 4 KB
  __shared__ __align__(16) f16 Bh[2][NEXP * BK];   // 2 x 16 KB
  __shared__ __align__(16) f16 Bl[2][NEXP * BK];   // 2 x 16 KB  => 80 KB total

  const int tid  = threadIdx.x;
  const int lane = tid & 63;
  const int w    = tid >> 6;                 // wave id 0..3 -> output cols w*64
  const int bm   = blockIdx.x * BM;
  const int kbase = blockIdx.y * ktiles * BK;
  float* Lp = L + (size_t)blockIdx.y * NTOK * NEXP;

  // A staging: thread -> row ar (0..63), k-chunk akq (0..3) of 8 f32
  const int ar  = tid >> 2;
  const int akq = tid & 3;
  const float* asrc = X + (size_t)(bm + ar) * DIM + akq * 8;

  // fragment read offsets (f16 elements)
  const int aoff = (lane & 15) * BK + (lane >> 4) * 8;             // + mi*512
  const int boff = (w * 64 + (lane & 15)) * BK + (lane >> 4) * 8;  // + ni*512

  f32x4 acc[4][4];
#pragma unroll
  for (int i = 0; i < 4; ++i)
#pragma unroll
    for (int j = 0; j < 4; ++j) acc[i][j] = 0.0f;

  float4 pa0, pa1;   // A prefetch registers

  auto aload = [&](int k0) {            // issue A global loads FIRST (oldest)
    pa0 = *reinterpret_cast<const float4*>(asrc + k0);
    pa1 = *reinterpret_cast<const float4*>(asrc + k0 + 4);
  };
  auto stageB = [&](int buf, int k0) {  // then 8 gload_lds (newest in vm queue)
#pragma unroll
    for (int j = 0; j < 4; ++j) {
      const int u0 = w * 256 + j * 64;
      const int u  = u0 + lane;
      const size_t goff = (size_t)(u >> 2) * DIM + k0 + (u & 3) * 8;
      __builtin_amdgcn_global_load_lds(
          (const __attribute__((address_space(1))) void*)(Whi + goff),
          (__attribute__((address_space(3))) void*)(&Bh[buf][u0 * 8]), 16, 0, 0);
      __builtin_amdgcn_global_load_lds(
          (const __attribute__((address_space(1))) void*)(Wlo + goff),
          (__attribute__((address_space(3))) void*)(&Bl[buf][u0 * 8]), 16, 0, 0);
    }
  };
  auto awrite = [&](int buf) {   // needs only pa0/pa1 -> minimal wait vmcnt(8)
    const float av[8] = {pa0.x, pa0.y, pa0.z, pa0.w, pa1.x, pa1.y, pa1.z, pa1.w};
    f16x8 hv, lv;
#pragma unroll
    for (int j = 0; j < 8; ++j) {
      const f16 h = (f16)av[j];
      hv[j] = h;
      lv[j] = (f16)(av[j] - (float)h);
    }
    *reinterpret_cast<f16x8*>(&Ah[buf][tid * 8]) = hv;
    *reinterpret_cast<f16x8*>(&Al[buf][tid * 8]) = lv;
  };
  auto compute = [&](int buf) {
    f16x8 ah[4], al4[4];
#pragma unroll
    for (int mi = 0; mi < 4; ++mi) {
      ah[mi]  = *reinterpret_cast<const f16x8*>(&Ah[buf][mi * 512 + aoff]);
      al4[mi] = *reinterpret_cast<const f16x8*>(&Al[buf][mi * 512 + aoff]);
    }
#pragma unroll
    for (int ni = 0; ni < 4; ++ni) {
      const f16x8 bh = *reinterpret_cast<const f16x8*>(&Bh[buf][ni * 512 + boff]);
      const f16x8 bl = *reinterpret_cast<const f16x8*>(&Bl[buf][ni * 512 + boff]);
#pragma unroll
      for (int mi = 0; mi < 4; ++mi) {
        acc[mi][ni] = __builtin_amdgcn_mfma_f32_16x16x32_f16(ah[mi],  bh, acc[mi][ni], 0, 0, 0);
        acc[mi][ni] = __builtin_amdgcn_mfma_f32_16x16x32_f16(al4[mi], bh, acc[mi][ni], 0, 0, 0);
        acc[mi][ni] = __builtin_amdgcn_mfma_f32_16x16x32_f16(ah[mi],  bl, acc[mi][ni], 0, 0, 0);
      }
    }
  };

  // prologue: stage tile 0 into buf 0 (awrite's wait lets B0 keep flying)
  aload(kbase);
  stageB(0, kbase);
  awrite(0);
  asm volatile("s_waitcnt lgkmcnt(0)" ::: "memory");
  __builtin_amdgcn_s_barrier();

  int cur = 0;
  for (int t = 0; t < ktiles - 1; ++t) {
    const int nxt = cur ^ 1;
    const int k1  = kbase + (t + 1) * BK;
    aload(k1);                          // A loads (oldest outstanding)
    stageB(nxt, k1);                    // 8 gload_lds for t+1 (stay in flight)
    awrite(nxt);                        // vmcnt(8): A done AND B_cur complete
    compute(cur);                       // MFMA on current buffer
    asm volatile("s_waitcnt lgkmcnt(0)" ::: "memory");  // ds reads+writes done
    __builtin_amdgcn_s_barrier();       // raw barrier: vm queue NOT drained
    cur = nxt;
  }
  // peeled last iteration: no prefetch covered B_last -> explicit drain
  asm volatile("s_waitcnt vmcnt(0)" ::: "memory");
  compute(cur);

  // epilogue: D col = lane&15, row = (lane>>4)*4 + j
  const int orow0 = bm + (lane >> 4) * 4;
  const int ocol  = w * 64 + (lane & 15);
#pragma unroll
  for (int mi = 0; mi < 4; ++mi)
#pragma unroll
    for (int j = 0; j < 4; ++j) {
      const int row = orow0 + mi * 16 + j;
#pragma unroll
      for (int ni = 0; ni < 4; ++ni)
        Lp[(size_t)row * NEXP + ocol + ni * 16] = acc[mi][ni][j];
    }
}

// ---------------- Routing: one wave (64 lanes) per token ---------------------
__global__ __launch_bounds__(256) void routing(const float* __restrict__ L,
                                               const float* __restrict__ bias,
                                               float* __restrict__ out,
                                               int nparts) {
  const int lane = threadIdx.x & 63;
  const int tok  = (int)((blockIdx.x * blockDim.x + threadIdx.x) >> 6);
  if (tok >= NTOK) return;

  float4 v = {0.f, 0.f, 0.f, 0.f};
  for (int p = 0; p < nparts; ++p) {
    const float4 t = reinterpret_cast<const float4*>(
        L + (size_t)p * NTOK * NEXP + (size_t)tok * NEXP)[lane];
    v.x += t.x; v.y += t.y; v.z += t.z; v.w += t.w;
  }

  float m = fmaxf(fmaxf(v.x, v.y), fmaxf(v.z, v.w));
#pragma unroll
  for (int off = 32; off; off >>= 1) m = fmaxf(m, __shfl_xor(m, off));
  float s0 = expf(v.x - m), s1 = expf(v.y - m), s2 = expf(v.z - m), s3 = expf(v.w - m);
  float sum = s0 + s1 + s2 + s3;
#pragma unroll
  for (int off = 32; off; off >>= 1) sum += __shfl_xor(sum, off);
  const float inv = 1.0f / sum;
  s0 *= inv; s1 *= inv; s2 *= inv; s3 *= inv;

  const float4 bb = reinterpret_cast<const float4*>(bias)[lane];
  float b0 = s0 + bb.x, b1 = s1 + bb.y, b2 = s2 + bb.z, b3 = s3 + bb.w;

  float m1 = fmaxf(b0, b1), m2 = fminf(b0, b1);
  if (b2 > m1) { m2 = m1; m1 = b2; } else m2 = fmaxf(m2, b2);
  if (b3 > m1) { m2 = m1; m1 = b3; } else m2 = fmaxf(m2, b3);
#pragma unroll
  for (int off = 1; off < 8; off <<= 1) {
    const float o1 = __shfl_xor(m1, off);
    const float o2 = __shfl_xor(m2, off);
    if (o1 > m1) { m2 = fmaxf(m1, o2); m1 = o1; } else m2 = fmaxf(m2, o1);
  }
  const float gscore = m1 + m2;

  float gs[8];
#pragma unroll
  for (int g = 0; g < 8; ++g) gs[g] = __shfl(gscore, g * 8);

  unsigned gsel = 0;
#pragma unroll
  for (int k = 0; k < 4; ++k) {
    float best = -INFINITY; int bi = 0;
#pragma unroll
    for (int g = 0; g < 8; ++g)
      if (!((gsel >> g) & 1u) && gs[g] > best) { best = gs[g]; bi = g; }
    gsel |= 1u << bi;
  }
  if (!((gsel >> (lane >> 3)) & 1u)) { b0 = b1 = b2 = b3 = -INFINITY; }

  float outw = 0.0f, outi = 0.0f;
  for (int k = 0; k < 8; ++k) {
    float bv = b0; int bi = 0;
    if (b1 > bv) { bv = b1; bi = 1; }
    if (b2 > bv) { bv = b2; bi = 2; }
    if (b3 > bv) { bv = b3; bi = 3; }
    float rv = bv; int ri = lane * 4 + bi;
#pragma unroll
    for (int off = 32; off; off >>= 1) {
      const float ov = __shfl_xor(rv, off);
      const int   oi = __shfl_xor(ri, off);
      if (ov > rv || (ov == rv && oi < ri)) { rv = ov; ri = oi; }
    }
    const int srcl = ri >> 2, slot = ri & 3;
    const float sv = (slot == 0) ? s0 : (slot == 1) ? s1 : (slot == 2) ? s2 : s3;
    const float wsel = __shfl(sv, srcl) * 2.5f;
    if (lane == k) { outw = wsel; outi = (float)ri; }
    if (lane == srcl) {
      if      (slot == 0) b0 = -INFINITY;
      else if (slot == 1) b1 = -INFINITY;
      else if (slot == 2) b2 = -INFINITY;
      else                b3 = -INFINITY;
    }
  }
  if (lane < 8) {
    out[(size_t)tok * 8 + lane] = outw;
    out[(size_t)NTOK * 8 + (size_t)tok * 8 + lane] = outi;
  }
}

extern "C" void kernel_launch(void* const* d_in, const int* in_sizes, int n_in,
                              void* d_out, int out_size, void* d_ws, size_t ws_size,
                              hipStream_t stream) {
  const float* x    = (const float*)d_in[0];
  const float* w    = (const float*)d_in[1];
  const float* bias = (const float*)d_in[2];
  float* out = (float*)d_out;

  const size_t part_bytes = (size_t)NTOK * NEXP * sizeof(float);     // 8 MB
  const size_t w_bytes    = (size_t)NEXP * DIM * sizeof(f16);        // 3.67 MB each
  int nparts = 1;
  for (int np = 8; np >= 1; np >>= 1)
    if ((size_t)np * part_bytes + 2 * w_bytes <= ws_size) { nparts = np; break; }

  float* logits = (float*)d_ws;
  f16* whi = (f16*)((char*)d_ws + (size_t)nparts * part_bytes);
  f16* wlo = whi + (size_t)NEXP * DIM;

  wconv<<<(NEXP * DIM) / (256 * 4), 256, 0, stream>>>(w, whi, wlo);

  const int ktiles = (DIM / BK) / nparts;   // 224 / nparts
  dim3 gridG(NTOK / BM, nparts);            // (128, nparts)
  gemm_mfma<<<gridG, 256, 0, stream>>>(x, whi, wlo, logits, ktiles);

  routing<<<NTOK / 4, 256, 0, stream>>>(logits, bias, out, nparts);
}

// Round 7
// 419.217 us; speedup vs baseline: 1.0114x; 1.0114x over previous
//
#include <hip/hip_runtime.h>
#include <cstddef>
#include <cstdint>

#define DIM   7168
#define NEXP  256
#define NTOK  8192
#define BM    64
#define BK    32

typedef _Float16 f16;
typedef __attribute__((ext_vector_type(8))) _Float16 f16x8;
typedef __attribute__((ext_vector_type(4))) float    f32x4;

// ---------------- W pre-convert: f32 -> f16 hi + f16 lo ---------------------
__global__ __launch_bounds__(256) void wconv(const float* __restrict__ W,
                                             f16* __restrict__ Whi,
                                             f16* __restrict__ Wlo) {
  const int i = (blockIdx.x * 256 + threadIdx.x) * 4;
  const float4 v = *reinterpret_cast<const float4*>(W + i);
  f16 h0 = (f16)v.x, h1 = (f16)v.y, h2 = (f16)v.z, h3 = (f16)v.w;
  f16 l0 = (f16)(v.x - (float)h0), l1 = (f16)(v.y - (float)h1);
  f16 l2 = (f16)(v.z - (float)h2), l3 = (f16)(v.w - (float)h3);
  __attribute__((ext_vector_type(4))) _Float16 hv = {h0, h1, h2, h3};
  __attribute__((ext_vector_type(4))) _Float16 lv = {l0, l1, l2, l3};
  *reinterpret_cast<decltype(hv)*>(Whi + i) = hv;
  *reinterpret_cast<decltype(lv)*>(Wlo + i) = lv;
}

// ---------------- MFMA GEMM: Lp[m][n] = sum_k X[m][k] * W[n][k] -------------
// fp16 3-term split. Software pipeline:
//   B: gload_lds 1 tile ahead into LDS dbuf (counted vmcnt, raw barriers)
//   A: global->reg 2 tiles ahead (two NAMED reg sets, loop unrolled x2)
// Per iter t: stageB(t+1); aload(t+2); awrite(t+1) [auto vmcnt(10): retires
// B_t + A_{t+1}, leaves B_{t+1}+A_{t+2} in flight]; compute(t); lgkm0; barrier.
__global__ __launch_bounds__(256, 2) void gemm_mfma(const float* __restrict__ X,
                                                    const f16* __restrict__ Whi,
                                                    const f16* __restrict__ Wlo,
                                                    float* __restrict__ L,
                                                    int ktiles) {
  __shared__ __align__(16) f16 Ah[2][BM * BK];     // 2 x 4 KB
  __shared__ __align__(16) f16 Al[2][BM * BK];     // 2 x 4 KB
  __shared__ __align__(16) f16 Bh[2][NEXP * BK];   // 2 x 16 KB
  __shared__ __align__(16) f16 Bl[2][NEXP * BK];   // 2 x 16 KB  => 80 KB total

  const int tid  = threadIdx.x;
  const int lane = tid & 63;
  const int w    = tid >> 6;                 // wave id 0..3 -> output cols w*64
  const int bm   = blockIdx.x * BM;
  const int kbase = blockIdx.y * ktiles * BK;
  float* Lp = L + (size_t)blockIdx.y * NTOK * NEXP;

  // A staging: thread -> row ar (0..63), k-chunk akq (0..3) of 8 f32
  const int ar  = tid >> 2;
  const int akq = tid & 3;
  const float* asrc = X + (size_t)(bm + ar) * DIM + akq * 8;

  // fragment read offsets (f16 elements)
  const int aoff = (lane & 15) * BK + (lane >> 4) * 8;             // + mi*512
  const int boff = (w * 64 + (lane & 15)) * BK + (lane >> 4) * 8;  // + ni*512

  f32x4 acc[4][4];
#pragma unroll
  for (int i = 0; i < 4; ++i)
#pragma unroll
    for (int j = 0; j < 4; ++j) acc[i][j] = 0.0f;

  // two NAMED A-prefetch register sets (static indexing, rule #20)
  float4 pe0, pe1, po0, po1;

  auto stageB = [&](int buf, int k0) {
#pragma unroll
    for (int j = 0; j < 4; ++j) {
      const int u0 = w * 256 + j * 64;
      const int u  = u0 + lane;
      const size_t goff = (size_t)(u >> 2) * DIM + k0 + (u & 3) * 8;
      __builtin_amdgcn_global_load_lds(
          (const __attribute__((address_space(1))) void*)(Whi + goff),
          (__attribute__((address_space(3))) void*)(&Bh[buf][u0 * 8]), 16, 0, 0);
      __builtin_amdgcn_global_load_lds(
          (const __attribute__((address_space(1))) void*)(Wlo + goff),
          (__attribute__((address_space(3))) void*)(&Bl[buf][u0 * 8]), 16, 0, 0);
    }
  };
  auto awrite = [&](int buf, const float4& a0, const float4& a1) {
    const float av[8] = {a0.x, a0.y, a0.z, a0.w, a1.x, a1.y, a1.z, a1.w};
    f16x8 hv, lv;
#pragma unroll
    for (int j = 0; j < 8; ++j) {
      const f16 h = (f16)av[j];
      hv[j] = h;
      lv[j] = (f16)(av[j] - (float)h);
    }
    *reinterpret_cast<f16x8*>(&Ah[buf][tid * 8]) = hv;
    *reinterpret_cast<f16x8*>(&Al[buf][tid * 8]) = lv;
  };
  auto compute = [&](int buf) {
    f16x8 ah[4], al4[4];
#pragma unroll
    for (int mi = 0; mi < 4; ++mi) {
      ah[mi]  = *reinterpret_cast<const f16x8*>(&Ah[buf][mi * 512 + aoff]);
      al4[mi] = *reinterpret_cast<const f16x8*>(&Al[buf][mi * 512 + aoff]);
    }
#pragma unroll
    for (int ni = 0; ni < 4; ++ni) {
      const f16x8 bh = *reinterpret_cast<const f16x8*>(&Bh[buf][ni * 512 + boff]);
      const f16x8 bl = *reinterpret_cast<const f16x8*>(&Bl[buf][ni * 512 + boff]);
#pragma unroll
      for (int mi = 0; mi < 4; ++mi) {
        acc[mi][ni] = __builtin_amdgcn_mfma_f32_16x16x32_f16(ah[mi],  bh, acc[mi][ni], 0, 0, 0);
        acc[mi][ni] = __builtin_amdgcn_mfma_f32_16x16x32_f16(al4[mi], bh, acc[mi][ni], 0, 0, 0);
        acc[mi][ni] = __builtin_amdgcn_mfma_f32_16x16x32_f16(ah[mi],  bl, acc[mi][ni], 0, 0, 0);
      }
    }
  };

  // ---- prologue: tile0 staged; A_1 in flight (odd set) ----
  pe0 = *reinterpret_cast<const float4*>(asrc + kbase);
  pe1 = *reinterpret_cast<const float4*>(asrc + kbase + 4);
  stageB(0, kbase);
  awrite(0, pe0, pe1);              // waits A_0 only (B_0 stays in flight)
  po0 = *reinterpret_cast<const float4*>(asrc + kbase + BK);
  po1 = *reinterpret_cast<const float4*>(asrc + kbase + BK + 4);
  asm volatile("s_waitcnt lgkmcnt(0)" ::: "memory");
  __builtin_amdgcn_s_barrier();

  // ---- steady state: unrolled x2 (ktiles is even, >= 4 for all nparts) ----
  int t = 0;
  for (; t + 3 < ktiles; t += 2) {
    // even iter: cur = buf0
    stageB(1, kbase + (t + 1) * BK);
    pe0 = *reinterpret_cast<const float4*>(asrc + kbase + (t + 2) * BK);
    pe1 = *reinterpret_cast<const float4*>(asrc + kbase + (t + 2) * BK + 4);
    awrite(1, po0, po1);            // auto vmcnt(10): retires B_t + A_{t+1}
    compute(0);
    asm volatile("s_waitcnt lgkmcnt(0)" ::: "memory");
    __builtin_amdgcn_s_barrier();
    // odd iter: cur = buf1
    stageB(0, kbase + (t + 2) * BK);
    po0 = *reinterpret_cast<const float4*>(asrc + kbase + (t + 3) * BK);
    po1 = *reinterpret_cast<const float4*>(asrc + kbase + (t + 3) * BK + 4);
    awrite(0, pe0, pe1);
    compute(1);
    asm volatile("s_waitcnt lgkmcnt(0)" ::: "memory");
    __builtin_amdgcn_s_barrier();
  }
  // ---- tail: t == ktiles-2 (cur = buf0), A_{K-1} sits in odd set ----
  stageB(1, kbase + (ktiles - 1) * BK);
  awrite(1, po0, po1);              // auto vmcnt(8): retires B_{K-2} + A_{K-1}
  compute(0);
  asm volatile("s_waitcnt lgkmcnt(0)" ::: "memory");
  __builtin_amdgcn_s_barrier();
  asm volatile("s_waitcnt vmcnt(0)" ::: "memory");   // B_{K-1} landed
  __builtin_amdgcn_sched_barrier(0);
  compute(1);

  // epilogue: D col = lane&15, row = (lane>>4)*4 + j
  const int orow0 = bm + (lane >> 4) * 4;
  const int ocol  = w * 64 + (lane & 15);
#pragma unroll
  for (int mi = 0; mi < 4; ++mi)
#pragma unroll
    for (int j = 0; j < 4; ++j) {
      const int row = orow0 + mi * 16 + j;
#pragma unroll
      for (int ni = 0; ni < 4; ++ni)
        Lp[(size_t)row * NEXP + ocol + ni * 16] = acc[mi][ni][j];
    }
}

// ---------------- Routing: one wave (64 lanes) per token ---------------------
__global__ __launch_bounds__(256) void routing(const float* __restrict__ L,
                                               const float* __restrict__ bias,
                                               float* __restrict__ out,
                                               int nparts) {
  const int lane = threadIdx.x & 63;
  const int tok  = (int)((blockIdx.x * blockDim.x + threadIdx.x) >> 6);
  if (tok >= NTOK) return;

  float4 v = {0.f, 0.f, 0.f, 0.f};
  for (int p = 0; p < nparts; ++p) {
    const float4 t = reinterpret_cast<const float4*>(
        L + (size_t)p * NTOK * NEXP + (size_t)tok * NEXP)[lane];
    v.x += t.x; v.y += t.y; v.z += t.z; v.w += t.w;
  }

  float m = fmaxf(fmaxf(v.x, v.y), fmaxf(v.z, v.w));
#pragma unroll
  for (int off = 32; off; off >>= 1) m = fmaxf(m, __shfl_xor(m, off));
  float s0 = expf(v.x - m), s1 = expf(v.y - m), s2 = expf(v.z - m), s3 = expf(v.w - m);
  float sum = s0 + s1 + s2 + s3;
#pragma unroll
  for (int off = 32; off; off >>= 1) sum += __shfl_xor(sum, off);
  const float inv = 1.0f / sum;
  s0 *= inv; s1 *= inv; s2 *= inv; s3 *= inv;

  const float4 bb = reinterpret_cast<const float4*>(bias)[lane];
  float b0 = s0 + bb.x, b1 = s1 + bb.y, b2 = s2 + bb.z, b3 = s3 + bb.w;

  float m1 = fmaxf(b0, b1), m2 = fminf(b0, b1);
  if (b2 > m1) { m2 = m1; m1 = b2; } else m2 = fmaxf(m2, b2);
  if (b3 > m1) { m2 = m1; m1 = b3; } else m2 = fmaxf(m2, b3);
#pragma unroll
  for (int off = 1; off < 8; off <<= 1) {
    const float o1 = __shfl_xor(m1, off);
    const float o2 = __shfl_xor(m2, off);
    if (o1 > m1) { m2 = fmaxf(m1, o2); m1 = o1; } else m2 = fmaxf(m2, o1);
  }
  const float gscore = m1 + m2;

  float gs[8];
#pragma unroll
  for (int g = 0; g < 8; ++g) gs[g] = __shfl(gscore, g * 8);

  unsigned gsel = 0;
#pragma unroll
  for (int k = 0; k < 4; ++k) {
    float best = -INFINITY; int bi = 0;
#pragma unroll
    for (int g = 0; g < 8; ++g)
      if (!((gsel >> g) & 1u) && gs[g] > best) { best = gs[g]; bi = g; }
    gsel |= 1u << bi;
  }
  if (!((gsel >> (lane >> 3)) & 1u)) { b0 = b1 = b2 = b3 = -INFINITY; }

  float outw = 0.0f, outi = 0.0f;
  for (int k = 0; k < 8; ++k) {
    float bv = b0; int bi = 0;
    if (b1 > bv) { bv = b1; bi = 1; }
    if (b2 > bv) { bv = b2; bi = 2; }
    if (b3 > bv) { bv = b3; bi = 3; }
    float rv = bv; int ri = lane * 4 + bi;
#pragma unroll
    for (int off = 32; off; off >>= 1) {
      const float ov = __shfl_xor(rv, off);
      const int   oi = __shfl_xor(ri, off);
      if (ov > rv || (ov == rv && oi < ri)) { rv = ov; ri = oi; }
    }
    const int srcl = ri >> 2, slot = ri & 3;
    const float sv = (slot == 0) ? s0 : (slot == 1) ? s1 : (slot == 2) ? s2 : s3;
    const float wsel = __shfl(sv, srcl) * 2.5f;
    if (lane == k) { outw = wsel; outi = (float)ri; }
    if (lane == srcl) {
      if      (slot == 0) b0 = -INFINITY;
      else if (slot == 1) b1 = -INFINITY;
      else if (slot == 2) b2 = -INFINITY;
      else                b3 = -INFINITY;
    }
  }
  if (lane < 8) {
    out[(size_t)tok * 8 + lane] = outw;
    out[(size_t)NTOK * 8 + (size_t)tok * 8 + lane] = outi;
  }
}

extern "C" void kernel_launch(void* const* d_in, const int* in_sizes, int n_in,
                              void* d_out, int out_size, void* d_ws, size_t ws_size,
                              hipStream_t stream) {
  const float* x    = (const float*)d_in[0];
  const float* w    = (const float*)d_in[1];
  const float* bias = (const float*)d_in[2];
  float* out = (float*)d_out;

  const size_t part_bytes = (size_t)NTOK * NEXP * sizeof(float);     // 8 MB
  const size_t w_bytes    = (size_t)NEXP * DIM * sizeof(f16);        // 3.67 MB each
  int nparts = 1;
  for (int np = 8; np >= 1; np >>= 1)
    if ((size_t)np * part_bytes + 2 * w_bytes <= ws_size) { nparts = np; break; }

  float* logits = (float*)d_ws;
  f16* whi = (f16*)((char*)d_ws + (size_t)nparts * part_bytes);
  f16* wlo = whi + (size_t)NEXP * DIM;

  wconv<<<(NEXP * DIM) / (256 * 4), 256, 0, stream>>>(w, whi, wlo);

  const int ktiles = (DIM / BK) / nparts;   // 224 / nparts (even for all np)
  dim3 gridG(NTOK / BM, nparts);            // (128, nparts)
  gemm_mfma<<<gridG, 256, 0, stream>>>(x, whi, wlo, logits, ktiles);

  routing<<<NTOK / 4, 256, 0, stream>>>(logits, bias, out, nparts);
}

// Round 9
// 404.372 us; speedup vs baseline: 1.0485x; 1.0367x over previous
//
#include <hip/hip_runtime.h>
#include <cstddef>
#include <cstdint>

#define DIM   7168
#define NEXP  256
#define NTOK  8192
#define BM    128
#define BK    32

typedef _Float16 f16;
typedef __attribute__((ext_vector_type(8))) _Float16 f16x8;
typedef __attribute__((ext_vector_type(4))) float    f32x4;

// ---------------- W pre-convert: f32 -> f16 hi + f16 lo ---------------------
__global__ __launch_bounds__(256) void wconv(const float* __restrict__ W,
                                             f16* __restrict__ Whi,
                                             f16* __restrict__ Wlo) {
  const int i = (blockIdx.x * 256 + threadIdx.x) * 4;
  const float4 v = *reinterpret_cast<const float4*>(W + i);
  f16 h0 = (f16)v.x, h1 = (f16)v.y, h2 = (f16)v.z, h3 = (f16)v.w;
  f16 l0 = (f16)(v.x - (float)h0), l1 = (f16)(v.y - (float)h1);
  f16 l2 = (f16)(v.z - (float)h2), l3 = (f16)(v.w - (float)h3);
  __attribute__((ext_vector_type(4))) _Float16 hv = {h0, h1, h2, h3};
  __attribute__((ext_vector_type(4))) _Float16 lv = {l0, l1, l2, l3};
  *reinterpret_cast<decltype(hv)*>(Whi + i) = hv;
  *reinterpret_cast<decltype(lv)*>(Wlo + i) = lv;
}

// ---------------- MFMA GEMM: Lp[m][n] = dot(X[m,:], W[n,:]) -----------------
// fp16 3-term split (X=xh+xl, W=wh+wl; xh*wh + xl*wh + xh*wl).
// BM=128 x N=256 block, 4 waves, wave-tile 128x64 (acc 8x4), BK=32,
// single-buffer LDS (48 KB), r4-proven barrier discipline:
//   aload(f32->reg) ; sync ; stageB(gload_lds)+awrite ; sync ; compute.
__global__ __launch_bounds__(256, 2) void gemm_mfma(const float* __restrict__ X,
                                                    const f16* __restrict__ Whi,
                                                    const f16* __restrict__ Wlo,
                                                    float* __restrict__ L,
                                                    int ktiles) {
  __shared__ __align__(16) f16 Ah[BM * BK];     // 8 KB
  __shared__ __align__(16) f16 Al[BM * BK];     // 8 KB
  __shared__ __align__(16) f16 Bh[NEXP * BK];   // 16 KB
  __shared__ __align__(16) f16 Bl[NEXP * BK];   // 16 KB  => 48 KB total

  const int tid  = threadIdx.x;
  const int lane = tid & 63;
  const int w    = tid >> 6;                 // wave id 0..3 -> output cols w*64
  const int bm   = blockIdx.x * BM;
  const int kbase = blockIdx.y * ktiles * BK;
  float* Lp = L + (size_t)blockIdx.y * NTOK * NEXP;

  // A staging: thread -> row r (0..127), k-half h (0..1) of 16 f32
  const int ar = tid >> 1;
  const int ah_ = tid & 1;
  const float* asrc = X + (size_t)(bm + ar) * DIM + ah_ * 16;

  // fragment read offsets (f16 elements)
  const int aoff = (lane & 15) * BK + (lane >> 4) * 8;             // + mi*512
  const int boff = (w * 64 + (lane & 15)) * BK + (lane >> 4) * 8;  // + ni*512

  f32x4 acc[8][4];
#pragma unroll
  for (int i = 0; i < 8; ++i)
#pragma unroll
    for (int j = 0; j < 4; ++j) acc[i][j] = 0.0f;

  for (int t = 0; t < ktiles; ++t) {
    const int k0 = kbase + t * BK;

    // A f32 loads issued BEFORE the barrier: latency hides under the wait
    const float4 v0 = *reinterpret_cast<const float4*>(asrc + k0);
    const float4 v1 = *reinterpret_cast<const float4*>(asrc + k0 + 4);
    const float4 v2 = *reinterpret_cast<const float4*>(asrc + k0 + 8);
    const float4 v3 = *reinterpret_cast<const float4*>(asrc + k0 + 12);

    __syncthreads();   // previous tile fully consumed

    // B tiles: async global->LDS, linear dest (4 issues x hi/lo per thread)
#pragma unroll
    for (int j = 0; j < 4; ++j) {
      const int u0 = w * 256 + j * 64;
      const int u  = u0 + lane;
      const size_t goff = (size_t)(u >> 2) * DIM + k0 + (u & 3) * 8;
      __builtin_amdgcn_global_load_lds(
          (const __attribute__((address_space(1))) void*)(Whi + goff),
          (__attribute__((address_space(3))) void*)(&Bh[u0 * 8]), 16, 0, 0);
      __builtin_amdgcn_global_load_lds(
          (const __attribute__((address_space(1))) void*)(Wlo + goff),
          (__attribute__((address_space(3))) void*)(&Bl[u0 * 8]), 16, 0, 0);
    }

    // A: split 16 f32 -> f16 hi/lo, two 16B writes each
    {
      const float av[16] = {v0.x, v0.y, v0.z, v0.w, v1.x, v1.y, v1.z, v1.w,
                            v2.x, v2.y, v2.z, v2.w, v3.x, v3.y, v3.z, v3.w};
      f16x8 hA, lA, hB, lB;
#pragma unroll
      for (int j = 0; j < 8; ++j) {
        const f16 h = (f16)av[j];
        hA[j] = h; lA[j] = (f16)(av[j] - (float)h);
      }
#pragma unroll
      for (int j = 0; j < 8; ++j) {
        const f16 h = (f16)av[8 + j];
        hB[j] = h; lB[j] = (f16)(av[8 + j] - (float)h);
      }
      const int abase = ar * BK + ah_ * 16;
      *reinterpret_cast<f16x8*>(&Ah[abase])     = hA;
      *reinterpret_cast<f16x8*>(&Ah[abase + 8]) = hB;
      *reinterpret_cast<f16x8*>(&Al[abase])     = lA;
      *reinterpret_cast<f16x8*>(&Al[abase + 8]) = lB;
    }

    __syncthreads();   // drains vmcnt (gload_lds) + lgkm (A writes)

    // B fragments live across the mi loop (reused by all 8 mi)
    f16x8 bh[4], bl[4];
#pragma unroll
    for (int ni = 0; ni < 4; ++ni) {
      bh[ni] = *reinterpret_cast<const f16x8*>(&Bh[ni * 512 + boff]);
      bl[ni] = *reinterpret_cast<const f16x8*>(&Bl[ni * 512 + boff]);
    }
#pragma unroll
    for (int mi = 0; mi < 8; ++mi) {
      const f16x8 a_h = *reinterpret_cast<const f16x8*>(&Ah[mi * 512 + aoff]);
      const f16x8 a_l = *reinterpret_cast<const f16x8*>(&Al[mi * 512 + aoff]);
#pragma unroll
      for (int ni = 0; ni < 4; ++ni) {
        acc[mi][ni] = __builtin_amdgcn_mfma_f32_16x16x32_f16(a_h, bh[ni], acc[mi][ni], 0, 0, 0);
        acc[mi][ni] = __builtin_amdgcn_mfma_f32_16x16x32_f16(a_l, bh[ni], acc[mi][ni], 0, 0, 0);
        acc[mi][ni] = __builtin_amdgcn_mfma_f32_16x16x32_f16(a_h, bl[ni], acc[mi][ni], 0, 0, 0);
      }
    }
  }

  // epilogue: D col = lane&15, row = (lane>>4)*4 + j
  const int orow0 = bm + (lane >> 4) * 4;
  const int ocol  = w * 64 + (lane & 15);
#pragma unroll
  for (int mi = 0; mi < 8; ++mi)
#pragma unroll
    for (int j = 0; j < 4; ++j) {
      const int row = orow0 + mi * 16 + j;
#pragma unroll
      for (int ni = 0; ni < 4; ++ni)
        Lp[(size_t)row * NEXP + ocol + ni * 16] = acc[mi][ni][j];
    }
}

// ---------------- Routing: one wave (64 lanes) per token ---------------------
__global__ __launch_bounds__(256) void routing(const float* __restrict__ L,
                                               const float* __restrict__ bias,
                                               float* __restrict__ out,
                                               int nparts) {
  const int lane = threadIdx.x & 63;
  const int tok  = (int)((blockIdx.x * blockDim.x + threadIdx.x) >> 6);
  if (tok >= NTOK) return;

  float4 v = {0.f, 0.f, 0.f, 0.f};
  for (int p = 0; p < nparts; ++p) {
    const float4 t = reinterpret_cast<const float4*>(
        L + (size_t)p * NTOK * NEXP + (size_t)tok * NEXP)[lane];
    v.x += t.x; v.y += t.y; v.z += t.z; v.w += t.w;
  }

  float m = fmaxf(fmaxf(v.x, v.y), fmaxf(v.z, v.w));
#pragma unroll
  for (int off = 32; off; off >>= 1) m = fmaxf(m, __shfl_xor(m, off));
  float s0 = expf(v.x - m), s1 = expf(v.y - m), s2 = expf(v.z - m), s3 = expf(v.w - m);
  float sum = s0 + s1 + s2 + s3;
#pragma unroll
  for (int off = 32; off; off >>= 1) sum += __shfl_xor(sum, off);
  const float inv = 1.0f / sum;
  s0 *= inv; s1 *= inv; s2 *= inv; s3 *= inv;

  const float4 bb = reinterpret_cast<const float4*>(bias)[lane];
  float b0 = s0 + bb.x, b1 = s1 + bb.y, b2 = s2 + bb.z, b3 = s3 + bb.w;

  float m1 = fmaxf(b0, b1), m2 = fminf(b0, b1);
  if (b2 > m1) { m2 = m1; m1 = b2; } else m2 = fmaxf(m2, b2);
  if (b3 > m1) { m2 = m1; m1 = b3; } else m2 = fmaxf(m2, b3);
#pragma unroll
  for (int off = 1; off < 8; off <<= 1) {
    const float o1 = __shfl_xor(m1, off);
    const float o2 = __shfl_xor(m2, off);
    if (o1 > m1) { m2 = fmaxf(m1, o2); m1 = o1; } else m2 = fmaxf(m2, o1);
  }
  const float gscore = m1 + m2;

  float gs[8];
#pragma unroll
  for (int g = 0; g < 8; ++g) gs[g] = __shfl(gscore, g * 8);

  unsigned gsel = 0;
#pragma unroll
  for (int k = 0; k < 4; ++k) {
    float best = -INFINITY; int bi = 0;
#pragma unroll
    for (int g = 0; g < 8; ++g)
      if (!((gsel >> g) & 1u) && gs[g] > best) { best = gs[g]; bi = g; }
    gsel |= 1u << bi;
  }
  if (!((gsel >> (lane >> 3)) & 1u)) { b0 = b1 = b2 = b3 = -INFINITY; }

  float outw = 0.0f, outi = 0.0f;
  for (int k = 0; k < 8; ++k) {
    float bv = b0; int bi = 0;
    if (b1 > bv) { bv = b1; bi = 1; }
    if (b2 > bv) { bv = b2; bi = 2; }
    if (b3 > bv) { bv = b3; bi = 3; }
    float rv = bv; int ri = lane * 4 + bi;
#pragma unroll
    for (int off = 32; off; off >>= 1) {
      const float ov = __shfl_xor(rv, off);
      const int   oi = __shfl_xor(ri, off);
      if (ov > rv || (ov == rv && oi < ri)) { rv = ov; ri = oi; }
    }
    const int srcl = ri >> 2, slot = ri & 3;
    const float sv = (slot == 0) ? s0 : (slot == 1) ? s1 : (slot == 2) ? s2 : s3;
    const float wsel = __shfl(sv, srcl) * 2.5f;
    if (lane == k) { outw = wsel; outi = (float)ri; }
    if (lane == srcl) {
      if      (slot == 0) b0 = -INFINITY;
      else if (slot == 1) b1 = -INFINITY;
      else if (slot == 2) b2 = -INFINITY;
      else                b3 = -INFINITY;
    }
  }
  if (lane < 8) {
    out[(size_t)tok * 8 + lane] = outw;
    out[(size_t)NTOK * 8 + (size_t)tok * 8 + lane] = outi;
  }
}

extern "C" void kernel_launch(void* const* d_in, const int* in_sizes, int n_in,
                              void* d_out, int out_size, void* d_ws, size_t ws_size,
                              hipStream_t stream) {
  const float* x    = (const float*)d_in[0];
  const float* w    = (const float*)d_in[1];
  const float* bias = (const float*)d_in[2];
  float* out = (float*)d_out;

  const size_t part_bytes = (size_t)NTOK * NEXP * sizeof(float);     // 8 MB
  const size_t w_bytes    = (size_t)NEXP * DIM * sizeof(f16);        // 3.67 MB each
  // nparts must divide 224 (= DIM/BK); prefer more parts for occupancy
  const int cand[7] = {16, 14, 8, 7, 4, 2, 1};
  int nparts = 1;
  for (int c = 0; c < 7; ++c)
    if ((size_t)cand[c] * part_bytes + 2 * w_bytes <= ws_size) { nparts = cand[c]; break; }

  float* logits = (float*)d_ws;
  f16* whi = (f16*)((char*)d_ws + (size_t)nparts * part_bytes);
  f16* wlo = whi + (size_t)NEXP * DIM;

  wconv<<<(NEXP * DIM) / (256 * 4), 256, 0, stream>>>(w, whi, wlo);

  const int ktiles = (DIM / BK) / nparts;   // 224 / nparts
  dim3 gridG(NTOK / BM, nparts);            // (64, nparts)
  gemm_mfma<<<gridG, 256, 0, stream>>>(x, whi, wlo, logits, ktiles);

  routing<<<NTOK / 4, 256, 0, stream>>>(logits, bias, out, nparts);
}